// Round 1
// baseline (169.458 us; speedup 1.0000x reference)
//
#include <hip/hip_runtime.h>
#include <hip/hip_bf16.h>
#include <stdint.h>

#define HEADS 8
#define DHEAD 64
#define DIM 512
#define NSEQ 2048
#define BATCH 2
#define NROWS (BATCH * NSEQ)      // 4096
#define QKV_N 1536
#define REL_ROWS 1025
#define REL_PITCH 1088            // padded to 17*64 so qrel GEMM needs no N-bounds

static constexpr float SCALE_LOG2E = 0.125f * 1.4426950408889634f;  // SCALE * log2(e)

typedef __attribute__((ext_vector_type(8))) short bf16x8;   // 8 bf16 (4 VGPRs)
typedef __attribute__((ext_vector_type(4))) float f32x4;

__device__ __forceinline__ uint16_t f2bf(float f) {
    union { float f; uint32_t u; } v{f};
    uint32_t r = (v.u + 0x7FFFu + ((v.u >> 16) & 1u)) >> 16;
    return (uint16_t)r;
}
__device__ __forceinline__ float bf2f(uint16_t u) {
    union { uint32_t u; float f; } v{(uint32_t)u << 16};
    return v.f;
}

// ---------------------------------------------------------------- prep: x->bf16, rel_emb->bf16 (padded)
__global__ void prep_misc(const float* __restrict__ x, const float* __restrict__ rel,
                          uint16_t* __restrict__ xb, uint16_t* __restrict__ relb) {
    int total = NROWS * DIM + REL_PITCH * DHEAD;
    for (int idx = blockIdx.x * blockDim.x + threadIdx.x; idx < total; idx += gridDim.x * blockDim.x) {
        if (idx < NROWS * DIM) {
            xb[idx] = f2bf(x[idx]);
        } else {
            int i2 = idx - NROWS * DIM;
            relb[i2] = (i2 < REL_ROWS * DHEAD) ? f2bf(rel[i2]) : (uint16_t)0;
        }
    }
}

// ---------------------------------------------------------------- prep: transpose weights to [out][in] bf16
__global__ void prep_w(const float* __restrict__ Wq, const float* __restrict__ Wkv,
                       const float* __restrict__ Wo,
                       uint16_t* __restrict__ Wqkv_t, uint16_t* __restrict__ Wo_t) {
    __shared__ float tile[32][33];
    int bid = blockIdx.x;
    const float* src; uint16_t* dst; int J, ti, tj;
    if (bid < 256)      { src = Wq;  dst = Wqkv_t;             J = 512;  ti = bid >> 4;        tj = bid & 15; }
    else if (bid < 768) { int b = bid - 256; src = Wkv; dst = Wqkv_t + 512 * 512; J = 1024; ti = b >> 5; tj = b & 31; }
    else                { int b = bid - 768; src = Wo;  dst = Wo_t;   J = 512;  ti = b >> 4;        tj = b & 15; }
    int tx = threadIdx.x & 31, ty = threadIdx.x >> 5;
    int k0 = ti * 32, j0 = tj * 32;
    #pragma unroll
    for (int i = 0; i < 4; i++) tile[ty + 8 * i][tx] = src[(size_t)(k0 + ty + 8 * i) * J + j0 + tx];
    __syncthreads();
    #pragma unroll
    for (int i = 0; i < 4; i++) dst[(size_t)(j0 + ty + 8 * i) * 512 + k0 + tx] = f2bf(tile[tx][ty + 8 * i]);
}

// ---------------------------------------------------------------- 128x128 MFMA GEMM: C = A[M,K] * Bt[N,K]^T
template <bool BF16_OUT>
__global__ __launch_bounds__(256) void gemm128(const uint16_t* __restrict__ A,
                                               const uint16_t* __restrict__ Bt,
                                               void* __restrict__ Cout,
                                               const float* __restrict__ bias,
                                               int K, int ldc) {
    __shared__ char lds[32768];
    char* ldsA = lds;
    char* ldsB = lds + 16384;
    int m0 = blockIdx.x * 128, n0 = blockIdx.y * 128;
    int t = threadIdx.x, lane = t & 63, w = t >> 6;
    int wr = w >> 1, wc = w & 1;
    int l15 = lane & 15, lh = lane >> 4;
    f32x4 acc[4][4] = {};
    for (int k0 = 0; k0 < K; k0 += 64) {
        __syncthreads();
        {
            int row = t >> 3, ch = t & 7;
            #pragma unroll
            for (int p = 0; p < 4; p++) {
                int r = row + 32 * p;
                bf16x8 va = *(const bf16x8*)(A + (size_t)(m0 + r) * K + k0 + ch * 8);
                *(bf16x8*)(ldsA + r * 128 + ((ch * 16) ^ ((r & 7) << 4))) = va;
                bf16x8 vb = *(const bf16x8*)(Bt + (size_t)(n0 + r) * K + k0 + ch * 8);
                *(bf16x8*)(ldsB + r * 128 + ((ch * 16) ^ ((r & 7) << 4))) = vb;
            }
        }
        __syncthreads();
        #pragma unroll
        for (int kk = 0; kk < 2; kk++) {
            bf16x8 a[4], b[4];
            #pragma unroll
            for (int mi = 0; mi < 4; mi++) {
                int m = wr * 64 + mi * 16 + l15;
                a[mi] = *(const bf16x8*)(ldsA + m * 128 + ((kk * 64 + lh * 16) ^ ((m & 7) << 4)));
            }
            #pragma unroll
            for (int ni = 0; ni < 4; ni++) {
                int n = wc * 64 + ni * 16 + l15;
                b[ni] = *(const bf16x8*)(ldsB + n * 128 + ((kk * 64 + lh * 16) ^ ((n & 7) << 4)));
            }
            #pragma unroll
            for (int mi = 0; mi < 4; mi++)
                #pragma unroll
                for (int ni = 0; ni < 4; ni++)
                    acc[mi][ni] = __builtin_amdgcn_mfma_f32_16x16x32_bf16(a[mi], b[ni], acc[mi][ni], 0, 0, 0);
        }
    }
    #pragma unroll
    for (int mi = 0; mi < 4; mi++)
        #pragma unroll
        for (int ni = 0; ni < 4; ni++)
            #pragma unroll
            for (int i = 0; i < 4; i++) {
                int m = m0 + wr * 64 + mi * 16 + lh * 4 + i;
                int n = n0 + wc * 64 + ni * 16 + l15;
                float v = acc[mi][ni][i];
                if constexpr (BF16_OUT) ((uint16_t*)Cout)[(size_t)m * ldc + n] = f2bf(v);
                else                    ((float*)Cout)[(size_t)m * ldc + n] = v + bias[n];
            }
}

// ---------------------------------------------------------------- qrel[h, r, p] = q_h[r,:] . rel_emb[p,:]
__global__ __launch_bounds__(256) void qrel_gemm(const uint16_t* __restrict__ QKV,
                                                 const uint16_t* __restrict__ relb,
                                                 uint16_t* __restrict__ qrel) {
    __shared__ char lds[16384];
    char* ldsA = lds;
    char* ldsB = lds + 8192;
    int h = blockIdx.y;
    int r0 = blockIdx.x * 64;
    int t = threadIdx.x, lane = t & 63, w = t >> 6;
    int l15 = lane & 15, lh = lane >> 4;
    {
        int row = t >> 3, ch = t & 7;
        #pragma unroll
        for (int p = 0; p < 2; p++) {
            int r = row + 32 * p;
            bf16x8 v = *(const bf16x8*)(QKV + (size_t)(r0 + r) * QKV_N + h * 64 + ch * 8);
            *(bf16x8*)(ldsA + r * 128 + ((ch * 16) ^ ((r & 7) << 4))) = v;
        }
    }
    __syncthreads();
    bf16x8 afrag[2];
    #pragma unroll
    for (int kk = 0; kk < 2; kk++) {
        int m = w * 16 + l15;
        afrag[kk] = *(const bf16x8*)(ldsA + m * 128 + ((kk * 64 + lh * 16) ^ ((m & 7) << 4)));
    }
    for (int pb = 0; pb < REL_PITCH / 64; pb++) {
        int p0 = pb * 64;
        __syncthreads();
        {
            int row = t >> 3, ch = t & 7;
            #pragma unroll
            for (int p = 0; p < 2; p++) {
                int r = row + 32 * p;
                bf16x8 v = *(const bf16x8*)(relb + (size_t)(p0 + r) * 64 + ch * 8);
                *(bf16x8*)(ldsB + r * 128 + ((ch * 16) ^ ((r & 7) << 4))) = v;
            }
        }
        __syncthreads();
        f32x4 acc[4] = {};
        #pragma unroll
        for (int kk = 0; kk < 2; kk++)
            #pragma unroll
            for (int ni = 0; ni < 4; ni++) {
                int n = ni * 16 + l15;
                bf16x8 b = *(const bf16x8*)(ldsB + n * 128 + ((kk * 64 + lh * 16) ^ ((n & 7) << 4)));
                acc[ni] = __builtin_amdgcn_mfma_f32_16x16x32_bf16(afrag[kk], b, acc[ni], 0, 0, 0);
            }
        #pragma unroll
        for (int ni = 0; ni < 4; ni++)
            #pragma unroll
            for (int i = 0; i < 4; i++) {
                int rr = r0 + w * 16 + lh * 4 + i;
                int p = p0 + ni * 16 + l15;
                qrel[((size_t)h * NROWS + rr) * REL_PITCH + p] = f2bf(acc[ni][i]);
            }
    }
}

// ---------------------------------------------------------------- flash attention with rel-pos gather
__global__ __launch_bounds__(512) void attn_kernel(const uint16_t* __restrict__ QKV,
                                                   const uint16_t* __restrict__ qrel,
                                                   uint16_t* __restrict__ attO) {
    __shared__ char lds[49152];   // Q 16K | K 8K | Vt 8K | P 8*2K
    char* ldsQ = lds;
    char* ldsK = lds + 16384;
    char* ldsV = lds + 24576;
    char* ldsP = lds + 32768;
    int qb = blockIdx.x, h = blockIdx.y, b = blockIdx.z;
    int t = threadIdx.x, lane = t & 63, w = t >> 6;
    int l15 = lane & 15, lh = lane >> 4;
    int n0 = qb * 128;
    size_t rowQ = (size_t)b * NSEQ + n0;

    {   // stage Q tile 128x64 (swizzled)
        int row = t >> 3, ch = t & 7;
        #pragma unroll
        for (int p = 0; p < 2; p++) {
            int r = row + 64 * p;
            bf16x8 v = *(const bf16x8*)(QKV + (rowQ + r) * QKV_N + h * 64 + ch * 8);
            *(bf16x8*)(ldsQ + r * 128 + ((ch * 16) ^ ((r & 7) << 4))) = v;
        }
    }
    __syncthreads();
    bf16x8 qf[2];
    #pragma unroll
    for (int kk = 0; kk < 2; kk++) {
        int m = w * 16 + l15;
        qf[kk] = *(const bf16x8*)(ldsQ + m * 128 + ((kk * 64 + lh * 16) ^ ((m & 7) << 4)));
    }

    f32x4 oacc[4] = {};
    float mrow[4], lrow[4];
    #pragma unroll
    for (int i = 0; i < 4; i++) { mrow[i] = -INFINITY; lrow[i] = 0.f; }
    const uint16_t* qrel_base = qrel + ((size_t)h * NROWS + (size_t)b * NSEQ) * REL_PITCH;
    char* myP = ldsP + w * 2048;

    for (int kv0 = 0; kv0 < NSEQ; kv0 += 64) {
        __syncthreads();
        {   // stage K (row-major, swizzled) and V (transposed [d][key], swizzled)
            int row = t >> 3, ch = t & 7;
            size_t gro = ((size_t)b * NSEQ + kv0 + row) * QKV_N + h * 64 + ch * 8;
            bf16x8 kvec = *(const bf16x8*)(QKV + gro + 512);
            *(bf16x8*)(ldsK + row * 128 + ((ch * 16) ^ ((row & 7) << 4))) = kvec;
            bf16x8 vvec = *(const bf16x8*)(QKV + gro + 1024);
            #pragma unroll
            for (int dd = 0; dd < 8; dd++) {
                int d = ch * 8 + dd;
                *(uint16_t*)(ldsV + d * 128 + ((row * 2) ^ ((d & 7) << 4))) = (uint16_t)vvec[dd];
            }
        }
        __syncthreads();

        // S = Q K^T  (per wave: 16 rows x 64 keys)
        f32x4 sacc[4] = {};
        #pragma unroll
        for (int kk = 0; kk < 2; kk++)
            #pragma unroll
            for (int nf = 0; nf < 4; nf++) {
                int n = nf * 16 + l15;
                bf16x8 bfv = *(const bf16x8*)(ldsK + n * 128 + ((kk * 64 + lh * 16) ^ ((n & 7) << 4)));
                sacc[nf] = __builtin_amdgcn_mfma_f32_16x16x32_bf16(qf[kk], bfv, sacc[nf], 0, 0, 0);
            }

        // add relative-position term (raw, unscaled)
        #pragma unroll
        for (int nf = 0; nf < 4; nf++) {
            int j = kv0 + nf * 16 + l15;
            #pragma unroll
            for (int i = 0; i < 4; i++) {
                int n = n0 + w * 16 + lh * 4 + i;
                int d = n - j;
                d = d < -512 ? -512 : (d > 512 ? 512 : d);
                sacc[nf][i] += bf2f(qrel_base[(size_t)n * REL_PITCH + d + 512]);
            }
        }

        // online softmax
        float ptile[4][4];
        float alpha[4];
        #pragma unroll
        for (int i = 0; i < 4; i++) {
            float mx = fmaxf(fmaxf(sacc[0][i], sacc[1][i]), fmaxf(sacc[2][i], sacc[3][i]));
            #pragma unroll
            for (int off = 1; off < 16; off <<= 1) mx = fmaxf(mx, __shfl_xor(mx, off));
            float mnew = fmaxf(mrow[i], mx);
            alpha[i] = exp2f((mrow[i] - mnew) * SCALE_LOG2E);
            mrow[i] = mnew;
            float rs = 0.f;
            #pragma unroll
            for (int nf = 0; nf < 4; nf++) {
                float p = exp2f((sacc[nf][i] - mnew) * SCALE_LOG2E);
                ptile[nf][i] = p;
                rs += p;
            }
            #pragma unroll
            for (int off = 1; off < 16; off <<= 1) rs += __shfl_xor(rs, off);
            lrow[i] = lrow[i] * alpha[i] + rs;
        }
        #pragma unroll
        for (int nf = 0; nf < 4; nf++)
            #pragma unroll
            for (int i = 0; i < 4; i++)
                oacc[nf][i] *= alpha[i];

        // P -> LDS (bf16, swizzled), then PV
        #pragma unroll
        for (int nf = 0; nf < 4; nf++) {
            int col = nf * 16 + l15;
            #pragma unroll
            for (int i = 0; i < 4; i++) {
                int r = lh * 4 + i;
                *(uint16_t*)(myP + r * 128 + ((col * 2) ^ ((r & 7) << 4))) = f2bf(ptile[nf][i]);
            }
        }
        asm volatile("s_waitcnt lgkmcnt(0)" ::: "memory");
        #pragma unroll
        for (int kk = 0; kk < 2; kk++) {
            bf16x8 pa = *(const bf16x8*)(myP + l15 * 128 + ((kk * 64 + lh * 16) ^ ((l15 & 7) << 4)));
            #pragma unroll
            for (int nf = 0; nf < 4; nf++) {
                int d = nf * 16 + l15;
                bf16x8 vb = *(const bf16x8*)(ldsV + d * 128 + ((kk * 64 + lh * 16) ^ ((d & 7) << 4)));
                oacc[nf] = __builtin_amdgcn_mfma_f32_16x16x32_bf16(pa, vb, oacc[nf], 0, 0, 0);
            }
        }
    }

    #pragma unroll
    for (int nf = 0; nf < 4; nf++)
        #pragma unroll
        for (int i = 0; i < 4; i++) {
            int r = n0 + w * 16 + lh * 4 + i;
            int c = h * 64 + nf * 16 + l15;
            float v = oacc[nf][i] / lrow[i];
            attO[((size_t)b * NSEQ + r) * DIM + c] = f2bf(v);
        }
}

// ---------------------------------------------------------------- launch
extern "C" void kernel_launch(void* const* d_in, const int* in_sizes, int n_in,
                              void* d_out, int out_size, void* d_ws, size_t ws_size,
                              hipStream_t stream) {
    const float* x   = (const float*)d_in[0];
    const float* Wq  = (const float*)d_in[1];
    const float* Wkv = (const float*)d_in[2];
    const float* Wo  = (const float*)d_in[3];
    const float* bo  = (const float*)d_in[4];
    const float* rel = (const float*)d_in[5];
    char* ws = (char*)d_ws;
    uint16_t* Xb     = (uint16_t*)(ws);                 // 4096*512*2      = 4,194,304
    uint16_t* Wqkv_t = (uint16_t*)(ws + 4194304);       // 1536*512*2     = 1,572,864
    uint16_t* Wo_t   = (uint16_t*)(ws + 5767168);       // 512*512*2      = 524,288
    uint16_t* relb   = (uint16_t*)(ws + 6291456);       // 1088*64*2      = 139,264
    uint16_t* QKV    = (uint16_t*)(ws + 6430720);       // 4096*1536*2    = 12,582,912
    uint16_t* attO   = (uint16_t*)(ws + 19013632);      // 4096*512*2     = 4,194,304
    uint16_t* qrel   = (uint16_t*)(ws + 23207936);      // 8*4096*1088*2  = 71,303,168

    prep_misc<<<2048, 256, 0, stream>>>(x, rel, Xb, relb);
    prep_w<<<1024, 256, 0, stream>>>(Wq, Wkv, Wo, Wqkv_t, Wo_t);
    gemm128<true><<<dim3(32, 12), 256, 0, stream>>>(Xb, Wqkv_t, QKV, nullptr, 512, QKV_N);
    qrel_gemm<<<dim3(64, 8), 256, 0, stream>>>(QKV, relb, qrel);
    attn_kernel<<<dim3(16, 8, 2), 512, 0, stream>>>(QKV, qrel, attO);
    gemm128<false><<<dim3(32, 4), 256, 0, stream>>>(attO, Wo_t, (float*)d_out, bo, 512, DIM);
}

// Round 2
// 162.031 us; speedup vs baseline: 1.0458x; 1.0458x over previous
//
#include <hip/hip_runtime.h>
#include <hip/hip_bf16.h>
#include <stdint.h>

#define HEADS 8
#define DHEAD 64
#define DIM 512
#define NSEQ 2048
#define BATCH 2
#define NROWS (BATCH * NSEQ)      // 4096
#define QKV_N 1536
#define REL_ROWS 1025
#define REL_PITCH 1088            // padded to 17*64 so qrel GEMM needs no N-bounds
#define NSPLIT 2
#define KV_PER_SPLIT (NSEQ / NSPLIT)   // 1024

static constexpr float SCALE_LOG2E = 0.125f * 1.4426950408889634f;  // SCALE * log2(e)

typedef __attribute__((ext_vector_type(8))) short bf16x8;   // 8 bf16 (4 VGPRs)
typedef __attribute__((ext_vector_type(4))) float f32x4;

__device__ __forceinline__ uint16_t f2bf(float f) {
    union { float f; uint32_t u; } v{f};
    uint32_t r = (v.u + 0x7FFFu + ((v.u >> 16) & 1u)) >> 16;
    return (uint16_t)r;
}
__device__ __forceinline__ float bf2f(uint16_t u) {
    union { uint32_t u; float f; } v{(uint32_t)u << 16};
    return v.f;
}

// ---------------------------------------------------------------- prep: x->bf16, rel_emb->bf16 (padded)
__global__ void prep_misc(const float* __restrict__ x, const float* __restrict__ rel,
                          uint16_t* __restrict__ xb, uint16_t* __restrict__ relb) {
    int total = NROWS * DIM + REL_PITCH * DHEAD;
    for (int idx = blockIdx.x * blockDim.x + threadIdx.x; idx < total; idx += gridDim.x * blockDim.x) {
        if (idx < NROWS * DIM) {
            xb[idx] = f2bf(x[idx]);
        } else {
            int i2 = idx - NROWS * DIM;
            relb[i2] = (i2 < REL_ROWS * DHEAD) ? f2bf(rel[i2]) : (uint16_t)0;
        }
    }
}

// ---------------------------------------------------------------- prep: transpose weights to [out][in] bf16
__global__ void prep_w(const float* __restrict__ Wq, const float* __restrict__ Wkv,
                       const float* __restrict__ Wo,
                       uint16_t* __restrict__ Wqkv_t, uint16_t* __restrict__ Wo_t) {
    __shared__ float tile[32][33];
    int bid = blockIdx.x;
    const float* src; uint16_t* dst; int J, ti, tj;
    if (bid < 256)      { src = Wq;  dst = Wqkv_t;             J = 512;  ti = bid >> 4;        tj = bid & 15; }
    else if (bid < 768) { int b = bid - 256; src = Wkv; dst = Wqkv_t + 512 * 512; J = 1024; ti = b >> 5; tj = b & 31; }
    else                { int b = bid - 768; src = Wo;  dst = Wo_t;   J = 512;  ti = b >> 4;        tj = b & 15; }
    int tx = threadIdx.x & 31, ty = threadIdx.x >> 5;
    int k0 = ti * 32, j0 = tj * 32;
    #pragma unroll
    for (int i = 0; i < 4; i++) tile[ty + 8 * i][tx] = src[(size_t)(k0 + ty + 8 * i) * J + j0 + tx];
    __syncthreads();
    #pragma unroll
    for (int i = 0; i < 4; i++) dst[(size_t)(j0 + ty + 8 * i) * 512 + k0 + tx] = f2bf(tile[tx][ty + 8 * i]);
}

// ---------------------------------------------------------------- 128x128 MFMA GEMM: C = A[M,K] * Bt[N,K]^T
template <bool BF16_OUT>
__global__ __launch_bounds__(256) void gemm128(const uint16_t* __restrict__ A,
                                               const uint16_t* __restrict__ Bt,
                                               void* __restrict__ Cout,
                                               const float* __restrict__ bias,
                                               int K, int ldc) {
    __shared__ char lds[32768];
    char* ldsA = lds;
    char* ldsB = lds + 16384;
    int m0 = blockIdx.x * 128, n0 = blockIdx.y * 128;
    int t = threadIdx.x, lane = t & 63, w = t >> 6;
    int wr = w >> 1, wc = w & 1;
    int l15 = lane & 15, lh = lane >> 4;
    f32x4 acc[4][4] = {};
    for (int k0 = 0; k0 < K; k0 += 64) {
        __syncthreads();
        {
            int row = t >> 3, ch = t & 7;
            #pragma unroll
            for (int p = 0; p < 4; p++) {
                int r = row + 32 * p;
                bf16x8 va = *(const bf16x8*)(A + (size_t)(m0 + r) * K + k0 + ch * 8);
                *(bf16x8*)(ldsA + r * 128 + ((ch * 16) ^ ((r & 7) << 4))) = va;
                bf16x8 vb = *(const bf16x8*)(Bt + (size_t)(n0 + r) * K + k0 + ch * 8);
                *(bf16x8*)(ldsB + r * 128 + ((ch * 16) ^ ((r & 7) << 4))) = vb;
            }
        }
        __syncthreads();
        #pragma unroll
        for (int kk = 0; kk < 2; kk++) {
            bf16x8 a[4], b[4];
            #pragma unroll
            for (int mi = 0; mi < 4; mi++) {
                int m = wr * 64 + mi * 16 + l15;
                a[mi] = *(const bf16x8*)(ldsA + m * 128 + ((kk * 64 + lh * 16) ^ ((m & 7) << 4)));
            }
            #pragma unroll
            for (int ni = 0; ni < 4; ni++) {
                int n = wc * 64 + ni * 16 + l15;
                b[ni] = *(const bf16x8*)(ldsB + n * 128 + ((kk * 64 + lh * 16) ^ ((n & 7) << 4)));
            }
            #pragma unroll
            for (int mi = 0; mi < 4; mi++)
                #pragma unroll
                for (int ni = 0; ni < 4; ni++)
                    acc[mi][ni] = __builtin_amdgcn_mfma_f32_16x16x32_bf16(a[mi], b[ni], acc[mi][ni], 0, 0, 0);
        }
    }
    #pragma unroll
    for (int mi = 0; mi < 4; mi++)
        #pragma unroll
        for (int ni = 0; ni < 4; ni++)
            #pragma unroll
            for (int i = 0; i < 4; i++) {
                int m = m0 + wr * 64 + mi * 16 + lh * 4 + i;
                int n = n0 + wc * 64 + ni * 16 + l15;
                float v = acc[mi][ni][i];
                if constexpr (BF16_OUT) ((uint16_t*)Cout)[(size_t)m * ldc + n] = f2bf(v);
                else                    ((float*)Cout)[(size_t)m * ldc + n] = v + bias[n];
            }
}

// ---------------------------------------------------------------- qrel[h, r, p] = q_h[r,:] . rel_emb[p,:]
__global__ __launch_bounds__(256) void qrel_gemm(const uint16_t* __restrict__ QKV,
                                                 const uint16_t* __restrict__ relb,
                                                 uint16_t* __restrict__ qrel) {
    __shared__ char lds[16384];
    char* ldsA = lds;
    char* ldsB = lds + 8192;
    int h = blockIdx.y;
    int r0 = blockIdx.x * 64;
    int t = threadIdx.x, lane = t & 63, w = t >> 6;
    int l15 = lane & 15, lh = lane >> 4;
    {
        int row = t >> 3, ch = t & 7;
        #pragma unroll
        for (int p = 0; p < 2; p++) {
            int r = row + 32 * p;
            bf16x8 v = *(const bf16x8*)(QKV + (size_t)(r0 + r) * QKV_N + h * 64 + ch * 8);
            *(bf16x8*)(ldsA + r * 128 + ((ch * 16) ^ ((r & 7) << 4))) = v;
        }
    }
    __syncthreads();
    bf16x8 afrag[2];
    #pragma unroll
    for (int kk = 0; kk < 2; kk++) {
        int m = w * 16 + l15;
        afrag[kk] = *(const bf16x8*)(ldsA + m * 128 + ((kk * 64 + lh * 16) ^ ((m & 7) << 4)));
    }
    for (int pb = 0; pb < REL_PITCH / 64; pb++) {
        int p0 = pb * 64;
        __syncthreads();
        {
            int row = t >> 3, ch = t & 7;
            #pragma unroll
            for (int p = 0; p < 2; p++) {
                int r = row + 32 * p;
                bf16x8 v = *(const bf16x8*)(relb + (size_t)(p0 + r) * 64 + ch * 8);
                *(bf16x8*)(ldsB + r * 128 + ((ch * 16) ^ ((r & 7) << 4))) = v;
            }
        }
        __syncthreads();
        f32x4 acc[4] = {};
        #pragma unroll
        for (int kk = 0; kk < 2; kk++)
            #pragma unroll
            for (int ni = 0; ni < 4; ni++) {
                int n = ni * 16 + l15;
                bf16x8 b = *(const bf16x8*)(ldsB + n * 128 + ((kk * 64 + lh * 16) ^ ((n & 7) << 4)));
                acc[ni] = __builtin_amdgcn_mfma_f32_16x16x32_bf16(afrag[kk], b, acc[ni], 0, 0, 0);
            }
        #pragma unroll
        for (int ni = 0; ni < 4; ni++)
            #pragma unroll
            for (int i = 0; i < 4; i++) {
                int rr = r0 + w * 16 + lh * 4 + i;
                int p = p0 + ni * 16 + l15;
                qrel[((size_t)h * NROWS + rr) * REL_PITCH + p] = f2bf(acc[ni][i]);
            }
    }
}

// ---------------------------------------------------------------- flash attention, KV-split, dbuf, prefetch
__global__ __launch_bounds__(512, 4) void attn_kernel(const uint16_t* __restrict__ QKV,
                                                      const uint16_t* __restrict__ qrel,
                                                      float* __restrict__ Opart,
                                                      float* __restrict__ mlpart) {
    __shared__ char lds[65536];   // Q 16K | KV dbuf 2x(K 8K + V 8K) | P 8x2K
    char* ldsQ = lds;
    char* ldsKV = lds + 16384;
    char* ldsP = lds + 49152;
    int qb = blockIdx.x, h = blockIdx.y;
    int b = blockIdx.z >> 1, sp = blockIdx.z & 1;
    int t = threadIdx.x, lane = t & 63, w = t >> 6;
    int l15 = lane & 15, lh = lane >> 4;
    int row = t >> 3, ch = t & 7;
    int n0 = qb * 128;
    int kvbase = sp * KV_PER_SPLIT;
    size_t rowQ = (size_t)b * NSEQ + n0;

    {   // stage Q tile 128x64 (swizzled)
        #pragma unroll
        for (int p = 0; p < 2; p++) {
            int r = row + 64 * p;
            bf16x8 v = *(const bf16x8*)(QKV + (rowQ + r) * QKV_N + h * 64 + ch * 8);
            *(bf16x8*)(ldsQ + r * 128 + ((ch * 16) ^ ((r & 7) << 4))) = v;
        }
    }
    __syncthreads();
    bf16x8 qf[2];
    #pragma unroll
    for (int kk = 0; kk < 2; kk++) {
        int m = w * 16 + l15;
        qf[kk] = *(const bf16x8*)(ldsQ + m * 128 + ((kk * 64 + lh * 16) ^ ((m & 7) << 4)));
    }

    f32x4 oacc[4] = {};
    float mrow[4], lrow[4];
    #pragma unroll
    for (int i = 0; i < 4; i++) { mrow[i] = -INFINITY; lrow[i] = 0.f; }
    const uint16_t* qrel_base = qrel + ((size_t)h * NROWS + (size_t)b * NSEQ) * REL_PITCH;
    char* myP = ldsP + w * 2048;

    // prologue: load tile 0 K/V to regs
    bf16x8 kreg, vreg;
    {
        size_t gro = ((size_t)b * NSEQ + kvbase + row) * QKV_N + h * 64 + ch * 8;
        kreg = *(const bf16x8*)(QKV + gro + 512);
        vreg = *(const bf16x8*)(QKV + gro + 1024);
    }

    const int NT = KV_PER_SPLIT / 64;   // 16
    for (int tt = 0; tt < NT; ++tt) {
        char* ldsK = ldsKV + (tt & 1) * 16384;
        char* ldsV = ldsK + 8192;
        // write staged regs -> LDS buf[tt&1]
        *(bf16x8*)(ldsK + row * 128 + ((ch * 16) ^ ((row & 7) << 4))) = kreg;
        #pragma unroll
        for (int dd = 0; dd < 8; dd++) {
            int d = ch * 8 + dd;
            int s = dd ^ ch;   // (d&7) ^ ((d>>3)&7)
            *(uint16_t*)(ldsV + d * 128 + 2 * (row ^ (s << 3))) = (uint16_t)vreg[dd];
        }
        __syncthreads();
        // prefetch next K/V tile
        if (tt + 1 < NT) {
            size_t gro = ((size_t)b * NSEQ + kvbase + (tt + 1) * 64 + row) * QKV_N + h * 64 + ch * 8;
            kreg = *(const bf16x8*)(QKV + gro + 512);
            vreg = *(const bf16x8*)(QKV + gro + 1024);
        }
        int kv0 = kvbase + tt * 64;

        // issue rel-bias gathers early (consumed after QK^T)
        uint16_t g[16];
        #pragma unroll
        for (int nf = 0; nf < 4; nf++) {
            int j = kv0 + nf * 16 + l15;
            #pragma unroll
            for (int i = 0; i < 4; i++) {
                int n = n0 + w * 16 + lh * 4 + i;
                int d = n - j;
                d = d < -512 ? -512 : (d > 512 ? 512 : d);
                g[nf * 4 + i] = qrel_base[(size_t)n * REL_PITCH + d + 512];
            }
        }

        // S = Q K^T  (per wave: 16 rows x 64 keys)
        f32x4 sacc[4] = {};
        #pragma unroll
        for (int kk = 0; kk < 2; kk++)
            #pragma unroll
            for (int nf = 0; nf < 4; nf++) {
                int n = nf * 16 + l15;
                bf16x8 bfv = *(const bf16x8*)(ldsK + n * 128 + ((kk * 64 + lh * 16) ^ ((n & 7) << 4)));
                sacc[nf] = __builtin_amdgcn_mfma_f32_16x16x32_bf16(qf[kk], bfv, sacc[nf], 0, 0, 0);
            }

        // add relative-position term (raw, unscaled)
        #pragma unroll
        for (int nf = 0; nf < 4; nf++)
            #pragma unroll
            for (int i = 0; i < 4; i++)
                sacc[nf][i] += bf2f(g[nf * 4 + i]);

        // online softmax; write P directly to LDS inside the loop
        float alpha[4];
        #pragma unroll
        for (int i = 0; i < 4; i++) {
            float mx = fmaxf(fmaxf(sacc[0][i], sacc[1][i]), fmaxf(sacc[2][i], sacc[3][i]));
            #pragma unroll
            for (int off = 1; off < 16; off <<= 1) mx = fmaxf(mx, __shfl_xor(mx, off));
            float mnew = fmaxf(mrow[i], mx);
            alpha[i] = exp2f((mrow[i] - mnew) * SCALE_LOG2E);
            mrow[i] = mnew;
            float rs = 0.f;
            int r = lh * 4 + i;
            #pragma unroll
            for (int nf = 0; nf < 4; nf++) {
                float p = exp2f((sacc[nf][i] - mnew) * SCALE_LOG2E);
                rs += p;
                int col = nf * 16 + l15;
                *(uint16_t*)(myP + r * 128 + ((col * 2) ^ ((r & 7) << 4))) = f2bf(p);
            }
            #pragma unroll
            for (int off = 1; off < 16; off <<= 1) rs += __shfl_xor(rs, off);
            lrow[i] = lrow[i] * alpha[i] + rs;
        }
        #pragma unroll
        for (int nf = 0; nf < 4; nf++)
            #pragma unroll
            for (int i = 0; i < 4; i++)
                oacc[nf][i] *= alpha[i];

        asm volatile("s_waitcnt lgkmcnt(0)" ::: "memory");
        #pragma unroll
        for (int kk = 0; kk < 2; kk++) {
            bf16x8 pa = *(const bf16x8*)(myP + l15 * 128 + ((kk * 64 + lh * 16) ^ ((l15 & 7) << 4)));
            #pragma unroll
            for (int nf = 0; nf < 4; nf++) {
                int d = nf * 16 + l15;
                int sd = (d & 7) ^ ((d >> 3) & 7);
                bf16x8 vb = *(const bf16x8*)(ldsV + d * 128 + 16 * ((kk * 4 + lh) ^ sd));
                oacc[nf] = __builtin_amdgcn_mfma_f32_16x16x32_bf16(pa, vb, oacc[nf], 0, 0, 0);
            }
        }
    }

    // epilogue: write unnormalized partial O (f32) + m/l per row
    size_t rbase = ((size_t)(sp * BATCH + b) * HEADS + h) * NSEQ;
    #pragma unroll
    for (int nf = 0; nf < 4; nf++)
        #pragma unroll
        for (int i = 0; i < 4; i++) {
            int r = n0 + w * 16 + lh * 4 + i;
            Opart[(rbase + r) * 64 + nf * 16 + l15] = oacc[nf][i];
        }
    if (l15 == 0) {
        #pragma unroll
        for (int i = 0; i < 4; i++) {
            int r = n0 + w * 16 + lh * 4 + i;
            mlpart[(rbase + r) * 2]     = mrow[i];
            mlpart[(rbase + r) * 2 + 1] = lrow[i];
        }
    }
}

// ---------------------------------------------------------------- combine the 2 KV-splits
__global__ __launch_bounds__(256) void combine_kernel(const float* __restrict__ Opart,
                                                      const float* __restrict__ mlpart,
                                                      uint16_t* __restrict__ attO) {
    int lane = threadIdx.x & 63;
    int R = blockIdx.x * 4 + (threadIdx.x >> 6);   // [0, 32768): (b*8+h)*2048 + n
    const int SPSTRIDE = BATCH * HEADS * NSEQ;     // 32768
    float m1 = mlpart[(size_t)R * 2], l1 = mlpart[(size_t)R * 2 + 1];
    float m2 = mlpart[((size_t)SPSTRIDE + R) * 2], l2 = mlpart[((size_t)SPSTRIDE + R) * 2 + 1];
    float M = fmaxf(m1, m2);
    float w1 = exp2f((m1 - M) * SCALE_LOG2E);
    float w2 = exp2f((m2 - M) * SCALE_LOG2E);
    float Linv = 1.f / (l1 * w1 + l2 * w2);
    float o1 = Opart[(size_t)R * 64 + lane];
    float o2 = Opart[((size_t)SPSTRIDE + R) * 64 + lane];
    float o = (o1 * w1 + o2 * w2) * Linv;
    int bh = R >> 11, n = R & 2047;
    int b = bh >> 3, hh = bh & 7;
    attO[((size_t)(b * NSEQ + n)) * DIM + hh * 64 + lane] = f2bf(o);
}

// ---------------------------------------------------------------- launch
extern "C" void kernel_launch(void* const* d_in, const int* in_sizes, int n_in,
                              void* d_out, int out_size, void* d_ws, size_t ws_size,
                              hipStream_t stream) {
    const float* x   = (const float*)d_in[0];
    const float* Wq  = (const float*)d_in[1];
    const float* Wkv = (const float*)d_in[2];
    const float* Wo  = (const float*)d_in[3];
    const float* bo  = (const float*)d_in[4];
    const float* rel = (const float*)d_in[5];
    char* ws = (char*)d_ws;
    uint16_t* Xb     = (uint16_t*)(ws);                 // 4096*512*2      = 4,194,304 (dead after QKV gemm)
    float*    mlp    = (float*)(ws);                    // 65536*2*4      = 524,288 (reuses Xb region)
    uint16_t* Wqkv_t = (uint16_t*)(ws + 4194304);       // 1536*512*2     = 1,572,864
    uint16_t* Wo_t   = (uint16_t*)(ws + 5767168);       // 512*512*2      = 524,288
    uint16_t* relb   = (uint16_t*)(ws + 6291456);       // 1088*64*2      = 139,264
    uint16_t* QKV    = (uint16_t*)(ws + 6430720);       // 4096*1536*2    = 12,582,912
    uint16_t* attO   = (uint16_t*)(ws + 19013632);      // 4096*512*2     = 4,194,304
    uint16_t* qrel   = (uint16_t*)(ws + 23207936);      // 8*4096*1088*2  = 71,303,168
    float*    Opart  = (float*)(ws + 94511104);         // 2*32768*64*4   = 16,777,216  (end 111,288,320)

    prep_misc<<<2048, 256, 0, stream>>>(x, rel, Xb, relb);
    prep_w<<<1024, 256, 0, stream>>>(Wq, Wkv, Wo, Wqkv_t, Wo_t);
    gemm128<true><<<dim3(32, 12), 256, 0, stream>>>(Xb, Wqkv_t, QKV, nullptr, 512, QKV_N);
    qrel_gemm<<<dim3(64, 8), 256, 0, stream>>>(QKV, relb, qrel);
    attn_kernel<<<dim3(16, 8, 4), 512, 0, stream>>>(QKV, qrel, Opart, mlp);
    combine_kernel<<<8192, 256, 0, stream>>>(Opart, mlp, attO);
    gemm128<false><<<dim3(32, 4), 256, 0, stream>>>(attO, Wo_t, (float*)d_out, bo, 512, DIM);
}